// Round 4
// baseline (321.868 us; speedup 1.0000x reference)
//
#include <hip/hip_runtime.h>
#include <math.h>

// SPP: out = concat(x, mp5(x), mp9(x), mp13(x)), x:(32,512,32,32) fp32.
// mp9 = mp5^2, mp13 = mp5^3; mp5 separable; H and V 1-D passes commute.
// One WAVE owns 2 planes + private LDS region: zero barriers, zero bpermute.
// Schedule (verified absmax=0 in R3):
//   stage->LDS, V1(col) -T-> H1(row): store p1 ; H2(row) -T-> V2(col):
//   store p2 (dword, coalesced across lanes) ; V3(col) -T-> H3(row): store p3.
// R4 change vs R3: rolling-window max5 (3 live pairwise maxes instead of a
// 31-element temp array) to eliminate register spills under
// __launch_bounds__(256,4)'s 128-VGPR budget.

constexpr int LSTR = 36;
constexpr int PLANE_W = 32 * LSTR;   // 1152 words / plane
constexpr int PAIR_W = 2 * PLANE_W;  // 2304 words / wave
constexpr int HW = 1024;

// In-place 5-wide max over a[0..31] with border clipping, rolling temps.
// out[i] = max(m[i-2], m[i], a[i+2]) where m[j] = max(a[j], a[j+1]).
__device__ __forceinline__ void max5_inplace(float a[32]) {
    float mp2 = fmaxf(a[0], a[1]);   // m[0]
    float mp1 = fmaxf(a[1], a[2]);   // m[1]
    float mc  = fmaxf(a[2], a[3]);   // m[2]
    const float r0 = fmaxf(mp2, a[2]);
    const float r1 = fmaxf(mp2, mc);
    a[0] = r0;
    a[1] = r1;
    #pragma unroll
    for (int i = 2; i <= 29; ++i) {
        const float t  = fmaxf(fmaxf(mp2, mc), a[i + 2]);
        const float mn = fmaxf(a[i + 1], a[i + 2]);   // m[i+1], pre-overwrite
        a[i] = t;
        mp2 = mp1; mp1 = mc; mc = mn;
    }
    // post-loop: mp2=m[28], mp1=m[29], mc=m[30]
    const float r30 = fmaxf(mp2, mc);
    a[31] = fmaxf(mp1, a[31]);
    a[30] = r30;
}

__global__ __launch_bounds__(256, 4) void spp_kernel(const float* __restrict__ x,
                                                     float* __restrict__ out) {
    __shared__ float lds[4 * PAIR_W];   // 36,864 B -> 4 blocks/CU (16 waves)

    const int t = threadIdx.x;
    const int wv = t >> 6;
    const int lane = t & 63;
    const int h = lane >> 5;
    const int sub = lane & 31;

    const int pair = (blockIdx.x << 2) + wv;   // 0..8191 (2 planes each)
    const int P0 = pair << 1;
    const int n = P0 >> 9;
    const int c0 = P0 & 511;

    const float* src = x + (size_t)pair * 2048;
    float* ob0 = out + ((size_t)n * 2048 + c0) * HW;           // identity chunk
    const size_t levbase = ((size_t)n * 2048 + (c0 + h)) * HW; // + p*512*HW

    float* L = lds + wv * PAIR_W;       // wave-private scratch
    float* Lp = L + h * PLANE_W;        // this lane's plane

    // ---- coalesced load, identity store, stage to LDS ----
    {
        float4 q[8];
        #pragma unroll
        for (int k = 0; k < 8; ++k) q[k] = *(const float4*)(src + k * 256 + lane * 4);
        #pragma unroll
        for (int k = 0; k < 8; ++k) *(float4*)(ob0 + k * 256 + lane * 4) = q[k];
        #pragma unroll
        for (int k = 0; k < 8; ++k) {
            const int e = k * 256 + lane * 4;
            const int w = ((e >> 10) * PLANE_W) + (((e >> 5) & 31) * LSTR) + (e & 31);
            *(float4*)(L + w) = q[k];
        }
    }

    float a[32];

    // ---- V1: column ownership (plane h, col sub) ----
    #pragma unroll
    for (int r = 0; r < 32; ++r) a[r] = Lp[r * LSTR + sub];
    max5_inplace(a);
    // transpose col->row
    #pragma unroll
    for (int r = 0; r < 32; ++r) Lp[r * LSTR + sub] = a[r];
    #pragma unroll
    for (int k = 0; k < 8; ++k)
        *(float4*)(&a[k * 4]) = *(const float4*)(Lp + sub * LSTR + k * 4);
    // ---- H1 -> p1 (row ownership), store ----
    max5_inplace(a);
    {
        float* o = out + levbase + (size_t)512 * HW + sub * 32;
        #pragma unroll
        for (int k = 0; k < 8; ++k) *(float4*)(o + k * 4) = *(const float4*)(&a[k * 4]);
    }

    // ---- H2 (row ownership) ----
    max5_inplace(a);
    // transpose row->col
    #pragma unroll
    for (int k = 0; k < 8; ++k)
        *(float4*)(Lp + sub * LSTR + k * 4) = *(const float4*)(&a[k * 4]);
    #pragma unroll
    for (int r = 0; r < 32; ++r) a[r] = Lp[r * LSTR + sub];
    // ---- V2 -> p2 (col ownership), store (dword, lane-coalesced) ----
    max5_inplace(a);
    {
        float* o = out + levbase + (size_t)1024 * HW + sub;
        #pragma unroll
        for (int r = 0; r < 32; ++r) o[r * 32] = a[r];
    }

    // ---- V3 (col ownership) ----
    max5_inplace(a);
    // transpose col->row
    #pragma unroll
    for (int r = 0; r < 32; ++r) Lp[r * LSTR + sub] = a[r];
    #pragma unroll
    for (int k = 0; k < 8; ++k)
        *(float4*)(&a[k * 4]) = *(const float4*)(Lp + sub * LSTR + k * 4);
    // ---- H3 -> p3 (row ownership), store ----
    max5_inplace(a);
    {
        float* o = out + levbase + (size_t)1536 * HW + sub * 32;
        #pragma unroll
        for (int k = 0; k < 8; ++k) *(float4*)(o + k * 4) = *(const float4*)(&a[k * 4]);
    }
}

extern "C" void kernel_launch(void* const* d_in, const int* in_sizes, int n_in,
                              void* d_out, int out_size, void* d_ws, size_t ws_size,
                              hipStream_t stream) {
    const float* x = (const float*)d_in[0];
    float* out = (float*)d_out;
    // 16384 planes / 2 planes-per-wave / 4 waves-per-block = 2048 blocks
    spp_kernel<<<2048, 256, 0, stream>>>(x, out);
}